// Round 3
// baseline (694.458 us; speedup 1.0000x reference)
//
#include <hip/hip_runtime.h>
#include <hip/hip_bf16.h>

#define B_  256
#define N_  32768
#define D_  1024
#define H_  16
#define DH_ 64
#define KSPLIT 32
#define STRIPE (N_ / KSPLIT)   // 1024 keys per split

typedef __attribute__((ext_vector_type(8))) short bf16x8;
typedef __attribute__((ext_vector_type(4))) float f32x4;

static __device__ __forceinline__ short f2bf(float f) {
    union { __hip_bfloat16 h; short s; } u;
    u.h = __float2bfloat16(f);
    return u.s;
}

static __device__ __forceinline__ bf16x8 pack8(float4 a, float4 b) {
    bf16x8 r;
    r[0] = f2bf(a.x); r[1] = f2bf(a.y); r[2] = f2bf(a.z); r[3] = f2bf(a.w);
    r[4] = f2bf(b.x); r[5] = f2bf(b.y); r[6] = f2bf(b.z); r[7] = f2bf(b.w);
    return r;
}

// async global->LDS DMA, 16B per lane; LDS dest = wave-uniform base + lane*16
static __device__ __forceinline__ void gload16(const void* g, void* l) {
    __builtin_amdgcn_global_load_lds(
        (const __attribute__((address_space(1))) void*)g,
        (__attribute__((address_space(3))) void*)l, 16, 0, 0);
}

// ---------------------------------------------------------------------------
// f32 -> bf16 convert (weights only)
// ---------------------------------------------------------------------------
__global__ __launch_bounds__(256)
void f2b_kernel(const float* __restrict__ in, short* __restrict__ out, int n4)
{
    int i = blockIdx.x * 256 + threadIdx.x;
    if (i < n4) {
        float4 v = ((const float4*)in)[i];
        ((short4*)out)[i] = make_short4(f2bf(v.x), f2bf(v.y), f2bf(v.z), f2bf(v.w));
    }
}

// ---------------------------------------------------------------------------
// Hybrid GEMM: C = alpha * P[MP,K] x Qb[MQ,K]^T
//   P  : f32, staged RAW to LDS via global_load_lds (16KB tile), converted to
//        bf16 at fragment-read time.
//   Qb : bf16 (pre-converted weights), staged via global_load_lds (8KB tile).
// Bank-conflict fix without LDS padding (global_load_lds forbids padding):
// swizzle WHICH 16B granule each lane fetches on the global side —
//   f32 tile  (8 granules/row): granule c stored at slot c ^ (r&7)
//   bf16 tile (4 granules/row): granule c stored at slot c ^ ((r>>1)&3)
// -> ds_read_b128 fragment reads are 2-way (free) in both tiles.
// SWAP=false: C[p][q]; SWAP=true: C[q][p] (transposed V projection).
// ---------------------------------------------------------------------------
template<bool SWAP>
__global__ __launch_bounds__(256, 2)
void gemm_hybrid(const float* __restrict__ P, const short* __restrict__ Qb,
                 short* __restrict__ C, int MP, int MQ, int K, int ldc, float alpha)
{
    __shared__ __align__(16) float Pf[128 * 32];   // 16 KB, granule-swizzled
    __shared__ __align__(16) short Qs[128 * 32];   // 8 KB, granule-swizzled

    const int tid  = threadIdx.x;
    const int wave = tid >> 6;
    const int lane = tid & 63;
    const int quad = lane >> 4;
    const int l16  = lane & 15;

    const int gp = MP >> 7, gq = MQ >> 7;
    const int bid = blockIdx.x;
    int bp, bq;
    if (gp >= 8) {                       // XCD swizzle: keep a p-stripe per XCD
        int xcd = bid & 7, w = bid >> 3, sp = gp >> 3;
        bp = xcd * sp + w / gq;
        bq = w % gq;
    } else { bp = bid / gq; bq = bid % gq; }

    const int wm = (wave & 1) * 64;
    const int wn = (wave >> 1) * 64;

    // ---- loop-invariant staging pointers (advanced by constant per iter)
    const char* gA[4]; char* lA[4];
#pragma unroll
    for (int j = 0; j < 4; ++j) {
        int s = j * 256 + tid;           // LDS slot 0..1023
        int r = s >> 3;                  // tile row
        int c = (s & 7) ^ (r & 7);       // logical granule (swizzle)
        gA[j] = (const char*)(P + (size_t)(bp * 128 + r) * K) + c * 16;
        lA[j] = (char*)Pf + s * 16;
    }
    const char* gW[2]; char* lW[2];
#pragma unroll
    for (int j = 0; j < 2; ++j) {
        int s = j * 256 + tid;           // LDS slot 0..511
        int r = s >> 2;
        int c = (s & 3) ^ ((r >> 1) & 3);
        gW[j] = (const char*)(Qb + (size_t)(bq * 128 + r) * K) + c * 16;
        lW[j] = (char*)Qs + s * 16;
    }

    // ---- loop-invariant fragment LDS byte offsets
    const int rowPf0 = SWAP ? wn : wm;   // Pf holds SWAP ? B-side : A-side
    const int rowQs0 = SWAP ? wm : wn;
    int offPf[4][2], offQs[4];
#pragma unroll
    for (int f = 0; f < 4; ++f) {
        int r = rowPf0 + f * 16 + l16;
        offPf[f][0] = (r * 8 + ((quad * 2)     ^ (r & 7))) * 16;
        offPf[f][1] = (r * 8 + ((quad * 2 + 1) ^ (r & 7))) * 16;
        int r2 = rowQs0 + f * 16 + l16;
        offQs[f] = (r2 * 4 + (quad ^ ((r2 >> 1) & 3))) * 16;
    }

    f32x4 acc[4][4];
#pragma unroll
    for (int i = 0; i < 4; ++i)
#pragma unroll
        for (int j = 0; j < 4; ++j) acc[i][j] = (f32x4){0.f, 0.f, 0.f, 0.f};

    for (int kt = 0; kt < K; kt += 32) {
        __syncthreads();
#pragma unroll
        for (int j = 0; j < 4; ++j) { gload16(gA[j], lA[j]); gA[j] += 128; }
#pragma unroll
        for (int j = 0; j < 2; ++j) { gload16(gW[j], lW[j]); gW[j] += 64; }
        __syncthreads();

        bf16x8 fp[4], fq[4];
#pragma unroll
        for (int f = 0; f < 4; ++f) {
            float4 a = *(const float4*)((const char*)Pf + offPf[f][0]);
            float4 b = *(const float4*)((const char*)Pf + offPf[f][1]);
            fp[f] = pack8(a, b);
            fq[f] = *(const bf16x8*)((const char*)Qs + offQs[f]);
        }
#pragma unroll
        for (int mi = 0; mi < 4; ++mi)
#pragma unroll
            for (int ni = 0; ni < 4; ++ni)
                acc[mi][ni] = __builtin_amdgcn_mfma_f32_16x16x32_bf16(
                    SWAP ? fq[mi] : fp[mi], SWAP ? fp[ni] : fq[ni],
                    acc[mi][ni], 0, 0, 0);
    }

    // C/D layout: col = lane&15, row = quad*4 + reg  [m89-verified]
    const int rb = (SWAP ? bq : bp) * 128;
    const int cb = (SWAP ? bp : bq) * 128;
#pragma unroll
    for (int mi = 0; mi < 4; ++mi)
#pragma unroll
        for (int ni = 0; ni < 4; ++ni)
#pragma unroll
            for (int reg = 0; reg < 4; ++reg) {
                int r = rb + wm + mi * 16 + quad * 4 + reg;
                int c = cb + wn + ni * 16 + l16;
                C[(size_t)r * ldc + c] = f2bf(acc[mi][ni][reg] * alpha);
            }
}

// ---------------------------------------------------------------------------
// Flash attention, transposed-score form (log2-domain softmax: qh is
// pre-scaled by 1/8 * log2(e), so weights = 2^(s-m)).
// Grid (KSPLIT, 2, 16 heads), 256 thr = 4 independent waves.
// ---------------------------------------------------------------------------
__global__ __launch_bounds__(256, 2)
void attn_kernel(const short* __restrict__ qh, const short* __restrict__ kh,
                 const short* __restrict__ vhT, float* __restrict__ partO,
                 float* __restrict__ partM, float* __restrict__ partL)
{
    const int st = blockIdx.x, qb2 = blockIdx.y, h = blockIdx.z;
    const int tid  = threadIdx.x;
    const int wave = tid >> 6;
    const int lane = tid & 63;
    const int quad = lane >> 4;
    const int l16  = lane & 15;

    __shared__ __align__(16) short Ps[4][32][72];   // per-wave P round-trip

    const int qbase = qb2 * 128 + wave * 32;
    const int hoff  = h * DH_;

    bf16x8 qfr[2][2];
#pragma unroll
    for (int qf = 0; qf < 2; ++qf)
#pragma unroll
        for (int ks = 0; ks < 2; ++ks)
            qfr[qf][ks] = *(const bf16x8*)(qh + (size_t)(qbase + qf * 16 + l16) * D_
                                           + hoff + ks * 32 + quad * 8);

    f32x4 ofrag[2][4];
#pragma unroll
    for (int qf = 0; qf < 2; ++qf)
#pragma unroll
        for (int dt = 0; dt < 4; ++dt) ofrag[qf][dt] = (f32x4){0.f, 0.f, 0.f, 0.f};
    float m_i[2] = {-__builtin_inff(), -__builtin_inff()};
    float l_i[2] = {0.f, 0.f};

    const int n0 = st * STRIPE;

    bf16x8 akf[4][2];
#pragma unroll
    for (int kf = 0; kf < 4; ++kf)
#pragma unroll
        for (int ks = 0; ks < 2; ++ks)
            akf[kf][ks] = *(const bf16x8*)(kh + (size_t)(n0 + kf * 16 + l16) * D_
                                           + hoff + ks * 32 + quad * 8);

    for (int ch = 0; ch < STRIPE; ch += 64) {
        const int nb = n0 + ch;

        // ---- S^T = K·Q^T
        f32x4 sf[4][2];
#pragma unroll
        for (int kf = 0; kf < 4; ++kf)
#pragma unroll
            for (int qf = 0; qf < 2; ++qf) sf[kf][qf] = (f32x4){0.f, 0.f, 0.f, 0.f};
#pragma unroll
        for (int ks = 0; ks < 2; ++ks)
#pragma unroll
            for (int kf = 0; kf < 4; ++kf)
#pragma unroll
                for (int qf = 0; qf < 2; ++qf)
                    sf[kf][qf] = __builtin_amdgcn_mfma_f32_16x16x32_bf16(
                        akf[kf][ks], qfr[qf][ks], sf[kf][qf], 0, 0, 0);

        // ---- V loads for this chunk (latency hidden by softmax)
        bf16x8 avf[4][2];
#pragma unroll
        for (int dt = 0; dt < 4; ++dt)
#pragma unroll
            for (int g = 0; g < 2; ++g)
                avf[dt][g] = *(const bf16x8*)(vhT + (size_t)(hoff + dt * 16 + l16) * N_
                                              + nb + g * 32 + quad * 8);

        // ---- prefetch K frags for next chunk
        const int nbn = (ch + 64 < STRIPE) ? nb + 64 : nb;
#pragma unroll
        for (int kf = 0; kf < 4; ++kf)
#pragma unroll
            for (int ks = 0; ks < 2; ++ks)
                akf[kf][ks] = *(const bf16x8*)(kh + (size_t)(nbn + kf * 16 + l16) * D_
                                               + hoff + ks * 32 + quad * 8);

        // ---- online softmax (log2 domain)
#pragma unroll
        for (int qf = 0; qf < 2; ++qf) {
            float mx = sf[0][qf][0];
#pragma unroll
            for (int kf = 0; kf < 4; ++kf)
#pragma unroll
                for (int r = 0; r < 4; ++r) mx = fmaxf(mx, sf[kf][qf][r]);
            mx = fmaxf(mx, __shfl_xor(mx, 16));
            mx = fmaxf(mx, __shfl_xor(mx, 32));
            float mn = fmaxf(m_i[qf], mx);
            float al = exp2f(m_i[qf] - mn);
            m_i[qf] = mn;
            float ps = 0.f;
#pragma unroll
            for (int kf = 0; kf < 4; ++kf) {
                float p0 = exp2f(sf[kf][qf][0] - mn);
                float p1 = exp2f(sf[kf][qf][1] - mn);
                float p2 = exp2f(sf[kf][qf][2] - mn);
                float p3 = exp2f(sf[kf][qf][3] - mn);
                ps += (p0 + p1) + (p2 + p3);
                *(short4*)&Ps[wave][qf * 16 + l16][kf * 16 + quad * 4] =
                    make_short4(f2bf(p0), f2bf(p1), f2bf(p2), f2bf(p3));
            }
            ps += __shfl_xor(ps, 16);
            ps += __shfl_xor(ps, 32);
            l_i[qf] = l_i[qf] * al + ps;
#pragma unroll
            for (int dt = 0; dt < 4; ++dt) ofrag[qf][dt] *= al;
        }

        // ---- O^T += V·P
#pragma unroll
        for (int qf = 0; qf < 2; ++qf)
#pragma unroll
            for (int g = 0; g < 2; ++g) {
                bf16x8 bP = *(const bf16x8*)&Ps[wave][qf * 16 + l16][g * 32 + quad * 8];
#pragma unroll
                for (int dt = 0; dt < 4; ++dt)
                    ofrag[qf][dt] = __builtin_amdgcn_mfma_f32_16x16x32_bf16(
                        avf[dt][g], bP, ofrag[qf][dt], 0, 0, 0);
            }
    }

    const int pid = ((h * KSPLIT + st) * 2 + qb2) * 4 + wave;
#pragma unroll
    for (int qf = 0; qf < 2; ++qf)
#pragma unroll
        for (int dt = 0; dt < 4; ++dt)
            *(f32x4*)&partO[((size_t)pid * 32 + qf * 16 + l16) * 64 + dt * 16 + quad * 4]
                = ofrag[qf][dt];
    if (quad == 0) {
#pragma unroll
        for (int qf = 0; qf < 2; ++qf) {
            partM[pid * 32 + qf * 16 + l16] = m_i[qf];
            partL[pid * 32 + qf * 16 + l16] = l_i[qf];
        }
    }
}

// ---------------------------------------------------------------------------
// Merge KSPLIT partials (log2 domain).
// ---------------------------------------------------------------------------
__global__ __launch_bounds__(256)
void merge_kernel(const float* __restrict__ partO, const float* __restrict__ partM,
                  const float* __restrict__ partL, float* __restrict__ out)
{
    int idx = blockIdx.x * 256 + threadIdx.x;   // 0 .. B*D-1
    int b   = idx >> 10;
    int col = idx & 1023;
    int h   = col >> 6;
    int d   = col & 63;
    int blk32 = b >> 5, rin = b & 31;
    int qb2 = blk32 >> 2, w = blk32 & 3;

    float mmax = -__builtin_inff();
#pragma unroll
    for (int st = 0; st < KSPLIT; ++st) {
        int pid = ((h * KSPLIT + st) * 2 + qb2) * 4 + w;
        mmax = fmaxf(mmax, partM[pid * 32 + rin]);
    }
    float L = 0.f, o = 0.f;
#pragma unroll
    for (int st = 0; st < KSPLIT; ++st) {
        int pid = ((h * KSPLIT + st) * 2 + qb2) * 4 + w;
        float c = exp2f(partM[pid * 32 + rin] - mmax);
        L += c * partL[pid * 32 + rin];
        o += c * partO[((size_t)pid * 32 + rin) * 64 + d];
    }
    out[idx] = o / L;
}

// ---------------------------------------------------------------------------
extern "C" void kernel_launch(void* const* d_in, const int* in_sizes, int n_in,
                              void* d_out, int out_size, void* d_ws, size_t ws_size,
                              hipStream_t stream) {
    const float* q   = (const float*)d_in[0];
    const float* k   = (const float*)d_in[1];
    const float* v   = (const float*)d_in[2];
    const float* W_q = (const float*)d_in[3];
    const float* W_k = (const float*)d_in[4];
    const float* W_v = (const float*)d_in[5];
    float* out = (float*)d_out;

    // workspace (~168 MB)
    short* qh  = (short*)d_ws;                    // 256x1024
    short* kh  = qh  + (size_t)B_ * D_;           // 32768x1024  (64 MB)
    short* vhT = kh  + (size_t)N_ * D_;           // 1024x32768  (64 MB)
    short* Wqb = vhT + (size_t)D_ * N_;           // 3 x 2 MB bf16 weights
    short* Wkb = Wqb + (size_t)D_ * D_;
    short* Wvb = Wkb + (size_t)D_ * D_;
    float* partO = (float*)(Wvb + (size_t)D_ * D_);   // 4096 x 32 x 64 (32 MB)
    float* partM = partO + (size_t)4096 * 32 * 64;
    float* partL = partM + (size_t)4096 * 32;

    dim3 blk(256);
    const int w4 = (D_ * D_) / 4;
    // 1/sqrt(64) * log2(e): softmax runs in exp2 domain
    const float alpha_q = 0.125f * 1.4426950408889634f;

    f2b_kernel<<<dim3(w4 / 256), blk, 0, stream>>>(W_q, Wqb, w4);
    f2b_kernel<<<dim3(w4 / 256), blk, 0, stream>>>(W_k, Wkb, w4);
    f2b_kernel<<<dim3(w4 / 256), blk, 0, stream>>>(W_v, Wvb, w4);

    gemm_hybrid<false><<<dim3(2 * 8), blk, 0, stream>>>(q, Wqb, qh, B_, D_, D_, D_, alpha_q);
    gemm_hybrid<false><<<dim3(256 * 8), blk, 0, stream>>>(k, Wkb, kh, N_, D_, D_, D_, 1.0f);
    gemm_hybrid<true><<<dim3(256 * 8), blk, 0, stream>>>(v, Wvb, vhT, N_, D_, D_, N_, 1.0f);

    attn_kernel<<<dim3(KSPLIT, 2, H_), blk, 0, stream>>>(qh, kh, vhT, partO, partM, partL);
    merge_kernel<<<dim3((B_ * D_) / 256), blk, 0, stream>>>(partO, partM, partL, out);
}

// Round 4
// 600.197 us; speedup vs baseline: 1.1571x; 1.1571x over previous
//
#include <hip/hip_runtime.h>
#include <hip/hip_bf16.h>

#define B_  256
#define N_  32768
#define D_  1024
#define H_  16
#define DH_ 64
#define KSPLIT 32
#define STRIPE (N_ / KSPLIT)   // 1024 keys per split

typedef __attribute__((ext_vector_type(8))) short bf16x8;
typedef __attribute__((ext_vector_type(4))) float f32x4;

static __device__ __forceinline__ short f2bf(float f) {
    union { __hip_bfloat16 h; short s; } u;
    u.h = __float2bfloat16(f);
    return u.s;
}

static __device__ __forceinline__ bf16x8 pack8(float4 a, float4 b) {
    bf16x8 r;
    r[0] = f2bf(a.x); r[1] = f2bf(a.y); r[2] = f2bf(a.z); r[3] = f2bf(a.w);
    r[4] = f2bf(b.x); r[5] = f2bf(b.y); r[6] = f2bf(b.z); r[7] = f2bf(b.w);
    return r;
}

// async global->LDS DMA, 16B/lane, contiguous lane order (coalesced)
static __device__ __forceinline__ void gload16(const void* g, void* l) {
    __builtin_amdgcn_global_load_lds(
        (const __attribute__((address_space(1))) void*)g,
        (__attribute__((address_space(3))) void*)l, 16, 0, 0);
}

// ---------------------------------------------------------------------------
// f32 -> bf16: 8 elems/thread, 16B stores. n8 = elements/8.
// ---------------------------------------------------------------------------
__global__ __launch_bounds__(256)
void f2b_kernel(const float* __restrict__ in, short* __restrict__ out, int n8)
{
    int i = blockIdx.x * 256 + threadIdx.x;
    if (i < n8) {
        float4 a = ((const float4*)in)[2 * i];
        float4 b = ((const float4*)in)[2 * i + 1];
        ((bf16x8*)out)[i] = pack8(a, b);
    }
}

// ---------------------------------------------------------------------------
// Pure-bf16 GEMM (m97 clone): C = alpha * P[MP,K] x Qb[MQ,K]^T, both bf16.
// 128x128 tile, BK=32, LDS 8+8 KB contiguous (DMA-staged, coalesced),
// 4 waves x 4x4 16x16x32 MFMA.  XCD swizzle: p-stripe per XCD, q-fast.
// SWAP=false: C[p][q];  SWAP=true: C[q][p] (transposed V projection).
// ---------------------------------------------------------------------------
template<bool SWAP>
__global__ __launch_bounds__(256, 2)
void gemm_bb(const short* __restrict__ P, const short* __restrict__ Qb,
             short* __restrict__ C, int MP, int MQ, int K, int ldc, float alpha)
{
    __shared__ __align__(16) short Ps_[128 * 32];   // 8 KB
    __shared__ __align__(16) short Qs_[128 * 32];   // 8 KB

    const int tid  = threadIdx.x;
    const int wave = tid >> 6;
    const int lane = tid & 63;
    const int quad = lane >> 4;
    const int l16  = lane & 15;

    const int gp = MP >> 7, gq = MQ >> 7;
    const int bid = blockIdx.x;
    int bp, bq;
    if (gp >= 8) {
        int xcd = bid & 7, w = bid >> 3, sp = gp >> 3;
        bp = xcd * sp + w / gq;
        bq = w % gq;
    } else { bp = bid / gq; bq = bid % gq; }

    const int wm = (wave & 1) * 64;
    const int wn = (wave >> 1) * 64;

    // staging: 512 granules (16B) per tile, 2 per thread per tile; contiguous
    const char* gP[2]; char* lP[2];
    const char* gW[2]; char* lW[2];
#pragma unroll
    for (int j = 0; j < 2; ++j) {
        int s = j * 256 + tid;           // slot 0..511
        int r = s >> 2, g = s & 3;       // row, 16B-granule in 64B row
        gP[j] = (const char*)(P + (size_t)(bp * 128 + r) * K) + g * 16;
        lP[j] = (char*)Ps_ + s * 16;
        gW[j] = (const char*)(Qb + (size_t)(bq * 128 + r) * K) + g * 16;
        lW[j] = (char*)Qs_ + s * 16;
    }

    const short* tileA = SWAP ? Qs_ : Ps_;
    const short* tileB = SWAP ? Ps_ : Qs_;

    f32x4 acc[4][4];
#pragma unroll
    for (int i = 0; i < 4; ++i)
#pragma unroll
        for (int j = 0; j < 4; ++j) acc[i][j] = (f32x4){0.f, 0.f, 0.f, 0.f};

    for (int kt = 0; kt < K; kt += 32) {
        __syncthreads();
#pragma unroll
        for (int j = 0; j < 2; ++j) {
            gload16(gP[j], lP[j]); gP[j] += 64;
            gload16(gW[j], lW[j]); gW[j] += 64;
        }
        __syncthreads();

        bf16x8 af[4], bf[4];
#pragma unroll
        for (int f = 0; f < 4; ++f) {
            af[f] = *(const bf16x8*)&tileA[(wm + f * 16 + l16) * 32 + quad * 8];
            bf[f] = *(const bf16x8*)&tileB[(wn + f * 16 + l16) * 32 + quad * 8];
        }
#pragma unroll
        for (int mi = 0; mi < 4; ++mi)
#pragma unroll
            for (int ni = 0; ni < 4; ++ni)
                acc[mi][ni] = __builtin_amdgcn_mfma_f32_16x16x32_bf16(
                    af[mi], bf[ni], acc[mi][ni], 0, 0, 0);
    }

    // C/D layout: col = lane&15, row = quad*4 + reg  [m89-verified]
    const int rb = (SWAP ? bq : bp) * 128;
    const int cb = (SWAP ? bp : bq) * 128;
#pragma unroll
    for (int mi = 0; mi < 4; ++mi)
#pragma unroll
        for (int ni = 0; ni < 4; ++ni)
#pragma unroll
            for (int reg = 0; reg < 4; ++reg) {
                int r = rb + wm + mi * 16 + quad * 4 + reg;
                int c = cb + wn + ni * 16 + l16;
                C[(size_t)r * ldc + c] = f2bf(acc[mi][ni][reg] * alpha);
            }
}

// ---------------------------------------------------------------------------
// Flash attention, transposed-score, log2-domain softmax (qh pre-scaled by
// 1/8*log2e).  Grid (KSPLIT, 16 heads), 4 independent waves x 32 q-rows.
// Both q-halves (qb2) processed per block so K/V frags are loaded ONCE.
// ---------------------------------------------------------------------------
__global__ __launch_bounds__(256, 2)
void attn_kernel(const short* __restrict__ qh, const short* __restrict__ kh,
                 const short* __restrict__ vhT, float* __restrict__ partO,
                 float* __restrict__ partM, float* __restrict__ partL)
{
    const int st = blockIdx.x, h = blockIdx.y;
    const int tid  = threadIdx.x;
    const int wave = tid >> 6;
    const int lane = tid & 63;
    const int quad = lane >> 4;
    const int l16  = lane & 15;

    __shared__ __align__(16) short Ps[4][32][72];   // per-wave P round-trip

    const int hoff = h * DH_;

    // Q fragments for both halves (L2-hot, hoisted)
    bf16x8 qfr[2][2][2];   // [qb2][qf][ks]
#pragma unroll
    for (int qb2 = 0; qb2 < 2; ++qb2)
#pragma unroll
        for (int qf = 0; qf < 2; ++qf)
#pragma unroll
            for (int ks = 0; ks < 2; ++ks)
                qfr[qb2][qf][ks] = *(const bf16x8*)
                    (qh + (size_t)(qb2 * 128 + wave * 32 + qf * 16 + l16) * D_
                        + hoff + ks * 32 + quad * 8);

    f32x4 ofrag[2][2][4];
    float m_i[2][2], l_i[2][2];
#pragma unroll
    for (int qb2 = 0; qb2 < 2; ++qb2)
#pragma unroll
        for (int qf = 0; qf < 2; ++qf) {
            m_i[qb2][qf] = -__builtin_inff();
            l_i[qb2][qf] = 0.f;
#pragma unroll
            for (int dt = 0; dt < 4; ++dt) ofrag[qb2][qf][dt] = (f32x4){0.f,0.f,0.f,0.f};
        }

    const int n0 = st * STRIPE;

    for (int ch = 0; ch < STRIPE; ch += 64) {
        const int nb = n0 + ch;

        // K and V fragments for this chunk (shared across both q-halves)
        bf16x8 akf[4][2], avf[4][2];
#pragma unroll
        for (int kf = 0; kf < 4; ++kf)
#pragma unroll
            for (int ks = 0; ks < 2; ++ks)
                akf[kf][ks] = *(const bf16x8*)(kh + (size_t)(nb + kf * 16 + l16) * D_
                                               + hoff + ks * 32 + quad * 8);
#pragma unroll
        for (int dt = 0; dt < 4; ++dt)
#pragma unroll
            for (int g = 0; g < 2; ++g)
                avf[dt][g] = *(const bf16x8*)(vhT + (size_t)(hoff + dt * 16 + l16) * N_
                                              + nb + g * 32 + quad * 8);

#pragma unroll
        for (int qb2 = 0; qb2 < 2; ++qb2) {
            // S^T = K·Q^T
            f32x4 sf[4][2];
#pragma unroll
            for (int kf = 0; kf < 4; ++kf)
#pragma unroll
                for (int qf = 0; qf < 2; ++qf) sf[kf][qf] = (f32x4){0.f,0.f,0.f,0.f};
#pragma unroll
            for (int ks = 0; ks < 2; ++ks)
#pragma unroll
                for (int kf = 0; kf < 4; ++kf)
#pragma unroll
                    for (int qf = 0; qf < 2; ++qf)
                        sf[kf][qf] = __builtin_amdgcn_mfma_f32_16x16x32_bf16(
                            akf[kf][ks], qfr[qb2][qf][ks], sf[kf][qf], 0, 0, 0);

            // online softmax (log2 domain)
#pragma unroll
            for (int qf = 0; qf < 2; ++qf) {
                float mx = sf[0][qf][0];
#pragma unroll
                for (int kf = 0; kf < 4; ++kf)
#pragma unroll
                    for (int r = 0; r < 4; ++r) mx = fmaxf(mx, sf[kf][qf][r]);
                mx = fmaxf(mx, __shfl_xor(mx, 16));
                mx = fmaxf(mx, __shfl_xor(mx, 32));
                float mn = fmaxf(m_i[qb2][qf], mx);
                float al = exp2f(m_i[qb2][qf] - mn);
                m_i[qb2][qf] = mn;
                float ps = 0.f;
#pragma unroll
                for (int kf = 0; kf < 4; ++kf) {
                    float p0 = exp2f(sf[kf][qf][0] - mn);
                    float p1 = exp2f(sf[kf][qf][1] - mn);
                    float p2 = exp2f(sf[kf][qf][2] - mn);
                    float p3 = exp2f(sf[kf][qf][3] - mn);
                    ps += (p0 + p1) + (p2 + p3);
                    *(short4*)&Ps[wave][qf * 16 + l16][kf * 16 + quad * 4] =
                        make_short4(f2bf(p0), f2bf(p1), f2bf(p2), f2bf(p3));
                }
                ps += __shfl_xor(ps, 16);
                ps += __shfl_xor(ps, 32);
                l_i[qb2][qf] = l_i[qb2][qf] * al + ps;
#pragma unroll
                for (int dt = 0; dt < 4; ++dt) ofrag[qb2][qf][dt] *= al;
            }

            // O^T += V·P   (per-wave LDS round-trip, no barrier)
#pragma unroll
            for (int qf = 0; qf < 2; ++qf)
#pragma unroll
                for (int g = 0; g < 2; ++g) {
                    bf16x8 bP = *(const bf16x8*)&Ps[wave][qf * 16 + l16][g * 32 + quad * 8];
#pragma unroll
                    for (int dt = 0; dt < 4; ++dt)
                        ofrag[qb2][qf][dt] = __builtin_amdgcn_mfma_f32_16x16x32_bf16(
                            avf[dt][g], bP, ofrag[qb2][qf][dt], 0, 0, 0);
                }
        }
    }

    const int pid = (h * KSPLIT + st) * 4 + wave;
#pragma unroll
    for (int qb2 = 0; qb2 < 2; ++qb2) {
        const size_t rowb = (size_t)(pid * 2 + qb2) * 32;
#pragma unroll
        for (int qf = 0; qf < 2; ++qf)
#pragma unroll
            for (int dt = 0; dt < 4; ++dt)
                *(f32x4*)&partO[(rowb + qf * 16 + l16) * 64 + dt * 16 + quad * 4]
                    = ofrag[qb2][qf][dt];
        if (quad == 0)
#pragma unroll
            for (int qf = 0; qf < 2; ++qf) {
                partM[rowb + qf * 16 + l16] = m_i[qb2][qf];
                partL[rowb + qf * 16 + l16] = l_i[qb2][qf];
            }
    }
}

// ---------------------------------------------------------------------------
// Merge KSPLIT partials (log2 domain).
// ---------------------------------------------------------------------------
__global__ __launch_bounds__(256)
void merge_kernel(const float* __restrict__ partO, const float* __restrict__ partM,
                  const float* __restrict__ partL, float* __restrict__ out)
{
    int idx = blockIdx.x * 256 + threadIdx.x;   // 0 .. B*D-1
    int b   = idx >> 10;
    int col = idx & 1023;
    int h   = col >> 6;
    int d   = col & 63;
    int qb2 = b >> 7, rr = b & 127;
    int w = rr >> 5, rin = rr & 31;

    float mmax = -__builtin_inff();
#pragma unroll
    for (int st = 0; st < KSPLIT; ++st) {
        int slot = (((h * KSPLIT + st) * 4 + w) * 2 + qb2) * 32 + rin;
        mmax = fmaxf(mmax, partM[slot]);
    }
    float L = 0.f, o = 0.f;
#pragma unroll
    for (int st = 0; st < KSPLIT; ++st) {
        int slot = (((h * KSPLIT + st) * 4 + w) * 2 + qb2) * 32 + rin;
        float c = exp2f(partM[slot] - mmax);
        L += c * partL[slot];
        o += c * partO[(size_t)slot * 64 + d];
    }
    out[idx] = o / L;
}

// ---------------------------------------------------------------------------
extern "C" void kernel_launch(void* const* d_in, const int* in_sizes, int n_in,
                              void* d_out, int out_size, void* d_ws, size_t ws_size,
                              hipStream_t stream) {
    const float* q   = (const float*)d_in[0];
    const float* k   = (const float*)d_in[1];
    const float* v   = (const float*)d_in[2];
    const float* W_q = (const float*)d_in[3];
    const float* W_k = (const float*)d_in[4];
    const float* W_v = (const float*)d_in[5];
    float* out = (float*)d_out;

    // workspace (~242 MB)
    short* qh  = (short*)d_ws;                    // 256x1024 bf16
    short* kh  = qh  + (size_t)B_ * D_;           // 32768x1024 bf16 (64 MB)
    short* vhT = kh  + (size_t)N_ * D_;           // 1024x32768 bf16 (64 MB)
    short* kvb = vhT + (size_t)D_ * N_;           // reused bf16 input (64 MB)
    short* qb  = kvb + (size_t)N_ * D_;           // 256x1024 bf16
    short* Wqb = qb  + (size_t)B_ * D_;           // 3 x 2 MB bf16 weights
    short* Wkb = Wqb + (size_t)D_ * D_;
    short* Wvb = Wkb + (size_t)D_ * D_;
    float* partO = (float*)(Wvb + (size_t)D_ * D_);   // 4096 x 32 x 64 f32 (33.5 MB)
    float* partM = partO + (size_t)4096 * 32 * 64;
    float* partL = partM + (size_t)4096 * 32;

    dim3 blk(256);
    const int w8  = (D_ * D_) / 8;     // weight: 131072 x 16B
    const int kv8 = (N_ * D_) / 8;     // k/v:    4194304 x 16B
    const int q8  = (B_ * D_) / 8;
    const float alpha_q = 0.125f * 1.4426950408889634f;  // 1/sqrt(64)*log2(e)

    f2b_kernel<<<dim3(w8 / 256), blk, 0, stream>>>(W_q, Wqb, w8);
    f2b_kernel<<<dim3(w8 / 256), blk, 0, stream>>>(W_k, Wkb, w8);
    f2b_kernel<<<dim3(w8 / 256), blk, 0, stream>>>(W_v, Wvb, w8);
    f2b_kernel<<<dim3(q8 / 256), blk, 0, stream>>>(q, qb, q8);

    // qh = (q @ W_q^T) * alpha_q
    gemm_bb<false><<<dim3(2 * 8), blk, 0, stream>>>(qb, Wqb, qh, B_, D_, D_, D_, alpha_q);

    // kh = k @ W_k^T
    f2b_kernel<<<dim3(kv8 / 256), blk, 0, stream>>>(k, kvb, kv8);
    gemm_bb<false><<<dim3(256 * 8), blk, 0, stream>>>(kvb, Wkb, kh, N_, D_, D_, D_, 1.0f);

    // vhT = (v @ W_v^T)^T   (kvb reused; stream order serializes)
    f2b_kernel<<<dim3(kv8 / 256), blk, 0, stream>>>(v, kvb, kv8);
    gemm_bb<true><<<dim3(256 * 8), blk, 0, stream>>>(kvb, Wvb, vhT, N_, D_, D_, N_, 1.0f);

    attn_kernel<<<dim3(KSPLIT, H_), blk, 0, stream>>>(qh, kh, vhT, partO, partM, partL);
    merge_kernel<<<dim3((B_ * D_) / 256), blk, 0, stream>>>(partO, partM, partL, out);
}